// Round 3
// baseline (211.403 us; speedup 1.0000x reference)
//
#include <hip/hip_runtime.h>
#include <hip/hip_bf16.h>
#include <stdint.h>

typedef __attribute__((ext_vector_type(8))) short bf16x8;
typedef __attribute__((ext_vector_type(4))) float f32x4;

__device__ __forceinline__ float bf2f(unsigned short u) {
    union { unsigned int i; float f; } z; z.i = ((unsigned int)u) << 16; return z.f;
}
__device__ __forceinline__ unsigned short f2bf(float f) {
    union { float f; unsigned int i; } z; z.f = f;
    unsigned int x = z.i;
    unsigned int r = x + 0x7fffu + ((x >> 16) & 1u);
    return (unsigned short)(r >> 16);
}

typedef const __attribute__((address_space(1))) unsigned int* gp_t;
typedef __attribute__((address_space(3))) unsigned int* lp_t;

__device__ __forceinline__ void gload_lds16(const void* g, void* l) {
    __builtin_amdgcn_global_load_lds((gp_t)g, (lp_t)l, 16, 0, 0);
}

// bijective XCD-aware remap (m204 form), decompose with mt fastest
__device__ __forceinline__ void xcd_swizzle(int& mt, int& nt, int& z) {
    const int GX = gridDim.x, GY = gridDim.y;
    const int nwg = GX * GY * gridDim.z;
    const int orig = blockIdx.x + GX * (blockIdx.y + GY * blockIdx.z);
    const int q = nwg >> 3, r = nwg & 7;
    const int xcd = orig & 7, pos = orig >> 3;
    const int wgid = (xcd < r ? xcd * (q + 1) : r * (q + 1) + (xcd - r) * q) + pos;
    mt = wgid % GX;
    const int t = wgid / GX;
    nt = t % GY;
    z = t / GY;
}

// ---------------- fp32 -> bf16 conversion (optionally scaled) ----------------
__global__ __launch_bounds__(256) void cvt_kernel(const float* __restrict__ in,
                                                  unsigned short* __restrict__ out,
                                                  int n4, float scale) {
    int i = blockIdx.x * 256 + threadIdx.x;
    int stride = gridDim.x * 256;
    for (; i < n4; i += stride) {
        float4 v = reinterpret_cast<const float4*>(in)[i];
        ushort4 u;
        u.x = f2bf(v.x * scale);
        u.y = f2bf(v.y * scale);
        u.z = f2bf(v.z * scale);
        u.w = f2bf(v.w * scale);
        reinterpret_cast<ushort4*>(out)[i] = u;
    }
}

// ---------------- deep-pipelined NT GEMM: C[M][N] = A[M][K] * B[N][K]^T -----
// BM=256, BN=128, BK=64. 512 threads = 8 waves (4M x 2N), per-wave 64x64 out.
// LDS: 2 K-tile buffers (A 256x64 + B 128x64 bf16 = 48KB each), 96KB total.
// T2: XOR-swizzled LDS (byte ^= (row&7)<<4) via pre-swizzled global source.
// T3/T4: 2 phases/K-tile, raw s_barrier + counted vmcnt(3) (drain only at end).
// T5: setprio(1) around 16-MFMA clusters.
// Race ledger: all frag ds_reads at P0 -> tile reads complete at P0-end
// barrier; stages into the in-use buffer only at P1 (tile t+2 head) and next
// P0 (tail, other buffer). vmcnt(3) at t's P1-end guarantees tile t+1 landed.
// MODE 1: bf16 out, causal tile skip (nt > 2*mt+1)
// MODE 2: fp32 out, causal K-limit (Keff = min(K, (mt+1)*256))
// MODE 3: fused QKV epilogue (nt<8 Q, <16 K, else V transposed into C2)
template<int MODE>
__global__ __launch_bounds__(512, 2) void gemm_nt(
    const unsigned short* __restrict__ A, int lda, long long sA,
    const unsigned short* __restrict__ B, int ldb, long long sB,
    void* __restrict__ C0, void* __restrict__ C1, void* __restrict__ C2,
    int ldc, long long sC, int K)
{
    int mt, nt, z;
    xcd_swizzle(mt, nt, z);
    if (MODE == 1 && nt > 2 * mt + 1) return;
    const unsigned short* Ab = A + (size_t)z * sA;
    const unsigned short* Bb = B + (size_t)z * sB;
    const int Keff = (MODE == 2) ? (((mt + 1) * 256 < K) ? (mt + 1) * 256 : K) : K;
    const int nk = Keff >> 6;

    __shared__ unsigned short As[2][256 * 64];
    __shared__ unsigned short Bs[2][128 * 64];

    const int tid = threadIdx.x;
    const int l = tid & 63, w = tid >> 6;
    const int wr = w >> 1, wc = w & 1;
    const int m0 = mt * 256, n0 = nt * 128;

    // staging: chunk = 64 rows x 64 cols (8KB). Wave w covers rows w*8..w*8+7,
    // lane covers (row = w*8 + l>>3, 16B slot = l&7). LDS dest is linear
    // (wave-uniform base + lane*16); global source col is pre-swizzled by the
    // same involution the reads use: col16 = (l&7) ^ (row&7), row&7 == l>>3.
    const int srow = w * 8 + (l >> 3);
    const int scol = ((l & 7) ^ (l >> 3)) * 8;
    const size_t ldst = (size_t)w * 1024 + (size_t)l * 16;

    auto stage_first3 = [&](int t, int b) {   // A chunks 0,1,2 (rows 0..191)
        const int k0 = t * 64;
        gload_lds16(Ab + (size_t)(m0 +   0 + srow) * lda + k0 + scol, (char*)&As[b][0] +     0 + ldst);
        gload_lds16(Ab + (size_t)(m0 +  64 + srow) * lda + k0 + scol, (char*)&As[b][0] +  8192 + ldst);
        gload_lds16(Ab + (size_t)(m0 + 128 + srow) * lda + k0 + scol, (char*)&As[b][0] + 16384 + ldst);
    };
    auto stage_last3 = [&](int t, int b) {    // A chunk 3 + B chunks 0,1
        const int k0 = t * 64;
        gload_lds16(Ab + (size_t)(m0 + 192 + srow) * lda + k0 + scol, (char*)&As[b][0] + 24576 + ldst);
        gload_lds16(Bb + (size_t)(n0 +   0 + srow) * ldb + k0 + scol, (char*)&Bs[b][0] +     0 + ldst);
        gload_lds16(Bb + (size_t)(n0 +  64 + srow) * ldb + k0 + scol, (char*)&Bs[b][0] +  8192 + ldst);
    };

    // swizzled frag reads (16B each): logical slot = kk*4 + (l>>4)
    auto lda_frag = [&](int b, int mi, int kk) -> bf16x8 {
        const int row = wr * 64 + mi * 16 + (l & 15);
        const int slot = (kk * 4 + (l >> 4)) ^ (row & 7);
        return *reinterpret_cast<const bf16x8*>((const char*)&As[b][0] + row * 128 + slot * 16);
    };
    auto ldb_frag = [&](int b, int ni, int kk) -> bf16x8 {
        const int row = wc * 64 + ni * 16 + (l & 15);
        const int slot = (kk * 4 + (l >> 4)) ^ (row & 7);
        return *reinterpret_cast<const bf16x8*>((const char*)&Bs[b][0] + row * 128 + slot * 16);
    };

    f32x4 acc[4][4] = {};

    // prologue: tile0 fully, tile1 head; vmcnt(3) -> tile0 landed
    stage_first3(0, 0);
    stage_last3(0, 0);
    if (nk > 1) {
        stage_first3(1, 1);
        asm volatile("s_waitcnt vmcnt(3)" ::: "memory");
    } else {
        asm volatile("s_waitcnt vmcnt(0)" ::: "memory");
    }
    __builtin_amdgcn_sched_barrier(0);
    __builtin_amdgcn_s_barrier();

    for (int t = 0; t < nk; ++t) {
        const int b = t & 1;
        // ---- P0: stage tail of tile t+1 (other buffer); read all frags; MFMA half 1
        if (t + 1 < nk) stage_last3(t + 1, b ^ 1);
        bf16x8 af[4][2], bfr[4][2];
        #pragma unroll
        for (int mi = 0; mi < 4; ++mi) {
            af[mi][0] = lda_frag(b, mi, 0);
            af[mi][1] = lda_frag(b, mi, 1);
        }
        #pragma unroll
        for (int ni = 0; ni < 4; ++ni) {
            bfr[ni][0] = ldb_frag(b, ni, 0);
            bfr[ni][1] = ldb_frag(b, ni, 1);
        }
        __builtin_amdgcn_s_setprio(1);
        #pragma unroll
        for (int mi = 0; mi < 4; ++mi)
            #pragma unroll
            for (int ni = 0; ni < 2; ++ni) {
                acc[mi][ni] = __builtin_amdgcn_mfma_f32_16x16x32_bf16(af[mi][0], bfr[ni][0], acc[mi][ni], 0, 0, 0);
                acc[mi][ni] = __builtin_amdgcn_mfma_f32_16x16x32_bf16(af[mi][1], bfr[ni][1], acc[mi][ni], 0, 0, 0);
            }
        __builtin_amdgcn_s_setprio(0);
        __builtin_amdgcn_s_barrier();          // all waves' tile-t reads done
        __builtin_amdgcn_sched_barrier(0);
        // ---- P1: stage head of tile t+2 (this buffer, now fully consumed); MFMA half 2
        if (t + 2 < nk) stage_first3(t + 2, b);
        __builtin_amdgcn_s_setprio(1);
        #pragma unroll
        for (int mi = 0; mi < 4; ++mi)
            #pragma unroll
            for (int ni = 2; ni < 4; ++ni) {
                acc[mi][ni] = __builtin_amdgcn_mfma_f32_16x16x32_bf16(af[mi][0], bfr[ni][0], acc[mi][ni], 0, 0, 0);
                acc[mi][ni] = __builtin_amdgcn_mfma_f32_16x16x32_bf16(af[mi][1], bfr[ni][1], acc[mi][ni], 0, 0, 0);
            }
        __builtin_amdgcn_s_setprio(0);
        if (t + 2 < nk) {
            asm volatile("s_waitcnt vmcnt(3)" ::: "memory");   // tile t+1 landed
        } else if (t + 1 < nk) {
            asm volatile("s_waitcnt vmcnt(0)" ::: "memory");   // final drain
        }
        __builtin_amdgcn_sched_barrier(0);
        __builtin_amdgcn_s_barrier();
        __builtin_amdgcn_sched_barrier(0);
    }

    // epilogue: C/D layout col = lane&15, row = (lane>>4)*4 + reg
    const int crow = (l >> 4) * 4, ccol = l & 15;
    if (MODE == 2) {
        float* C = (float*)C0 + (size_t)z * sC;
        #pragma unroll
        for (int mi = 0; mi < 4; ++mi)
            #pragma unroll
            for (int ni = 0; ni < 4; ++ni) {
                const size_t rbase = (size_t)(m0 + wr * 64 + mi * 16 + crow);
                const size_t cg = (size_t)(n0 + wc * 64 + ni * 16 + ccol);
                #pragma unroll
                for (int r = 0; r < 4; ++r)
                    C[(rbase + r) * ldc + cg] = acc[mi][ni][r];
            }
    } else if (MODE == 1) {
        unsigned short* C = (unsigned short*)C0 + (size_t)z * sC;
        #pragma unroll
        for (int mi = 0; mi < 4; ++mi)
            #pragma unroll
            for (int ni = 0; ni < 4; ++ni) {
                const size_t rbase = (size_t)(m0 + wr * 64 + mi * 16 + crow);
                const size_t cg = (size_t)(n0 + wc * 64 + ni * 16 + ccol);
                #pragma unroll
                for (int r = 0; r < 4; ++r)
                    C[(rbase + r) * ldc + cg] = f2bf(acc[mi][ni][r]);
            }
    } else { // MODE 3: fused QKV
        if (nt < 16) {
            unsigned short* C = (unsigned short*)(nt < 8 ? C0 : C1);
            const int cb = (nt < 8) ? n0 : n0 - 1024;
            #pragma unroll
            for (int mi = 0; mi < 4; ++mi)
                #pragma unroll
                for (int ni = 0; ni < 4; ++ni) {
                    const size_t rbase = (size_t)(m0 + wr * 64 + mi * 16 + crow);
                    const size_t cg = (size_t)(cb + wc * 64 + ni * 16 + ccol);
                    #pragma unroll
                    for (int r = 0; r < 4; ++r)
                        C[(rbase + r) * ldc + cg] = f2bf(acc[mi][ni][r]);
                }
        } else {
            unsigned short* Vt = (unsigned short*)C2;   // [1024][8192]
            #pragma unroll
            for (int mi = 0; mi < 4; ++mi)
                #pragma unroll
                for (int ni = 0; ni < 4; ++ni) {
                    const int rbase = m0 + wr * 64 + mi * 16 + crow;
                    const int o = (n0 - 2048) + wc * 64 + ni * 16 + ccol;
                    ushort4 u;
                    u.x = f2bf(acc[mi][ni][0]);
                    u.y = f2bf(acc[mi][ni][1]);
                    u.z = f2bf(acc[mi][ni][2]);
                    u.w = f2bf(acc[mi][ni][3]);
                    *reinterpret_cast<ushort4*>(&Vt[(size_t)o * 8192 + rbase]) = u;
                }
        }
    }
}

// ---------------- causal row softmax, in-place on bf16 scores ----------------
// one 256-thread block per row; reads cols <= q, writes cols < ((q>>8)+1)*256
// (exactly the extent the PV GEMM's causal K-limit will read)
__global__ __launch_bounds__(256) void softmax_causal(unsigned short* __restrict__ P) {
    const int S = 2048;
    const int gq = blockIdx.x;
    const int q = gq & (S - 1);
    unsigned short* row = P + (size_t)gq * S;
    const int t = threadIdx.x;
    const int c0 = t * 8;
    const int l = t & 63, w = t >> 6;
    const int wlim = ((q >> 8) + 1) << 8;
    const float NEG = -__builtin_huge_valf();

    float f[8];
    if (c0 <= q) {
        uint4 rv = *reinterpret_cast<const uint4*>(row + c0);
        unsigned short us[8];
        us[0] = rv.x & 0xffff; us[1] = rv.x >> 16;
        us[2] = rv.y & 0xffff; us[3] = rv.y >> 16;
        us[4] = rv.z & 0xffff; us[5] = rv.z >> 16;
        us[6] = rv.w & 0xffff; us[7] = rv.w >> 16;
        #pragma unroll
        for (int i = 0; i < 8; ++i)
            f[i] = (c0 + i <= q) ? bf2f(us[i]) : NEG;
    } else {
        #pragma unroll
        for (int i = 0; i < 8; ++i) f[i] = NEG;
    }

    float m = f[0];
    #pragma unroll
    for (int i = 1; i < 8; ++i) m = fmaxf(m, f[i]);
    #pragma unroll
    for (int o = 1; o < 64; o <<= 1) m = fmaxf(m, __shfl_xor(m, o));

    __shared__ float smax[4], ssum[4];
    if (l == 0) smax[w] = m;
    __syncthreads();
    m = fmaxf(fmaxf(smax[0], smax[1]), fmaxf(smax[2], smax[3]));

    float e[8];
    float s = 0.f;
    #pragma unroll
    for (int i = 0; i < 8; ++i) {
        e[i] = exp2f((f[i] - m) * 1.44269504f);   // exp(x-m); -inf -> 0
        s += e[i];
    }
    #pragma unroll
    for (int o = 1; o < 64; o <<= 1) s += __shfl_xor(s, o);
    if (l == 0) ssum[w] = s;
    __syncthreads();
    s = ssum[0] + ssum[1] + ssum[2] + ssum[3];
    const float inv = 1.0f / s;

    if (c0 < wlim) {
        uint4 ov;
        ov.x = f2bf(e[0] * inv) | ((unsigned int)f2bf(e[1] * inv) << 16);
        ov.y = f2bf(e[2] * inv) | ((unsigned int)f2bf(e[3] * inv) << 16);
        ov.z = f2bf(e[4] * inv) | ((unsigned int)f2bf(e[5] * inv) << 16);
        ov.w = f2bf(e[6] * inv) | ((unsigned int)f2bf(e[7] * inv) << 16);
        *reinterpret_cast<uint4*>(row + c0) = ov;
    }
}

extern "C" void kernel_launch(void* const* d_in, const int* in_sizes, int n_in,
                              void* d_out, int out_size, void* d_ws, size_t ws_size,
                              hipStream_t stream) {
    const float* x  = (const float*)d_in[0];
    const float* Wq = (const float*)d_in[1];
    const float* Wk = (const float*)d_in[2];
    const float* Wv = (const float*)d_in[3];
    float* out = (float*)d_out;

    const int Bz = 4, S = 2048, D = 1024;
    const int MS = Bz * S;       // 8192
    const int DD = D * D;

    char* ws = (char*)d_ws;
    unsigned short* xb   = (unsigned short*)(ws);                      // 16 MB [8192][1024]
    unsigned short* wqkv = (unsigned short*)(ws + (16ull << 20));      //  6 MB [3072][1024] (Wq pre-scaled 1/32)
    unsigned short* qb   = (unsigned short*)(ws + (22ull << 20));      // 16 MB [8192][1024]
    unsigned short* kb   = (unsigned short*)(ws + (38ull << 20));      // 16 MB [8192][1024]
    unsigned short* vt   = (unsigned short*)(ws + (54ull << 20));      // 16 MB [1024][8192] (V^T)
    unsigned short* sc   = (unsigned short*)(ws + (70ull << 20));      // 32 MB [4][2048][2048]

    // 1. bf16 conversion; fold softmax scale 1/sqrt(D)=1/32 into Wq
    cvt_kernel<<<2048, 256, 0, stream>>>(x,  xb, MS * D / 4, 1.0f);
    cvt_kernel<<<512,  256, 0, stream>>>(Wq, wqkv,          DD / 4, 0.03125f);
    cvt_kernel<<<512,  256, 0, stream>>>(Wk, wqkv + DD,     DD / 4, 1.0f);
    cvt_kernel<<<512,  256, 0, stream>>>(Wv, wqkv + 2 * DD, DD / 4, 1.0f);

    // 2. fused QKV projection: [8192][3072] = xb * Wqkv^T; V slice stored transposed
    gemm_nt<3><<<dim3(MS / 256, 24, 1), 512, 0, stream>>>(
        xb, D, 0, wqkv, D, 0, qb, kb, vt, D, 0, D);

    // 3. scores = Q * K^T per batch (bf16 out), skip strictly-upper tiles
    gemm_nt<1><<<dim3(S / 256, S / 128, Bz), 512, 0, stream>>>(
        qb, D, (long long)S * D, kb, D, (long long)S * D, sc, nullptr, nullptr,
        S, (long long)S * S, D);

    // 4. causal softmax in place (zero-fills up to the PV read extent)
    softmax_causal<<<MS, 256, 0, stream>>>(sc);

    // 5. out = P * V == P * Vt^T  (NT, fp32 out, causal K-limit)
    gemm_nt<2><<<dim3(S / 256, D / 128, Bz), 512, 0, stream>>>(
        sc, S, (long long)S * S, vt, MS, S, out, nullptr, nullptr,
        D, (long long)S * D, S);
}

// Round 4
// 185.819 us; speedup vs baseline: 1.1377x; 1.1377x over previous
//
#include <hip/hip_runtime.h>
#include <hip/hip_bf16.h>
#include <stdint.h>

typedef __attribute__((ext_vector_type(8))) short bf16x8;
typedef __attribute__((ext_vector_type(4))) float f32x4;

__device__ __forceinline__ float bf2f(unsigned short u) {
    union { unsigned int i; float f; } z; z.i = ((unsigned int)u) << 16; return z.f;
}
__device__ __forceinline__ unsigned short f2bf(float f) {
    union { float f; unsigned int i; } z; z.f = f;
    unsigned int x = z.i;
    unsigned int r = x + 0x7fffu + ((x >> 16) & 1u);
    return (unsigned short)(r >> 16);
}

typedef const __attribute__((address_space(1))) unsigned int* gp_t;
typedef __attribute__((address_space(3))) unsigned int* lp_t;

__device__ __forceinline__ void gload_lds16(const void* g, void* l) {
    __builtin_amdgcn_global_load_lds((gp_t)g, (lp_t)l, 16, 0, 0);
}

// bijective XCD-aware remap (m204 form), mt fastest
__device__ __forceinline__ void xcd_swizzle(int& mt, int& nt, int& z) {
    const int GX = gridDim.x, GY = gridDim.y;
    const int nwg = GX * GY * gridDim.z;
    const int orig = blockIdx.x + GX * (blockIdx.y + GY * blockIdx.z);
    const int q = nwg >> 3, r = nwg & 7;
    const int xcd = orig & 7, pos = orig >> 3;
    const int wgid = (xcd < r ? xcd * (q + 1) : r * (q + 1) + (xcd - r) * q) + pos;
    mt = wgid % GX;
    const int t = wgid / GX;
    nt = t % GY;
    z = t / GY;
}

// ---------------- fp32 -> bf16 conversion (optionally scaled) ----------------
__global__ __launch_bounds__(256) void cvt_kernel(const float* __restrict__ in,
                                                  unsigned short* __restrict__ out,
                                                  int n4, float scale) {
    int i = blockIdx.x * 256 + threadIdx.x;
    int stride = gridDim.x * 256;
    for (; i < n4; i += stride) {
        float4 v = reinterpret_cast<const float4*>(in)[i];
        ushort4 u;
        u.x = f2bf(v.x * scale);
        u.y = f2bf(v.y * scale);
        u.z = f2bf(v.z * scale);
        u.w = f2bf(v.w * scale);
        reinterpret_cast<ushort4*>(out)[i] = u;
    }
}

#define MFMA(a, b, c) __builtin_amdgcn_mfma_f32_16x16x32_bf16(a, b, c, 0, 0, 0)
#define SB() __builtin_amdgcn_sched_barrier(0)
#define BAR() __builtin_amdgcn_s_barrier()
#define LGKM0() asm volatile("s_waitcnt lgkmcnt(0)" ::: "memory")

// ======== m201-template NT GEMM: C[M][N] = A[M][K] * B[N][K]^T ========
// BM=BN=256, BK=64, 512 threads = 8 waves (2M x 4N), per-wave 128x64 out.
// LDS 128 KB: As[2]/Bs[2] 256x64 bf16 each, XOR-swizzled (slot ^= row&7) via
// pre-swizzled global source (both-sides involution).
// 4 phases per K-tile: P1 Q(0,0)[12 ds_reads], P2 Q(0,1)[4], P3 Q(1,1)[8],
// P4 Q(1,0)[0]; each phase: reads+stage -> bar -> lgkm0 -> prio1 16xMFMA prio0
// -> bar. Stage: P1 A0(t+1), P2 A1(t+1) [idle buf]; P3 B0(t+2), P4 B1(t+2)
// [current buf, after its B reads done]. vmcnt(4) once per K-tile at P4.
// MODE 1: bf16 out, causal tile skip (nt > mt). MODE 3: fused QKV epilogue.
template<int MODE>
__global__ __launch_bounds__(512, 2) void gemm256(
    const unsigned short* __restrict__ A, int lda, long long sA,
    const unsigned short* __restrict__ B, int ldb, long long sB,
    void* __restrict__ C0, void* __restrict__ C1, void* __restrict__ C2,
    int ldc, long long sC, int K)
{
    int mt, nt, z;
    xcd_swizzle(mt, nt, z);
    if (MODE == 1 && nt > mt) return;
    const unsigned short* Ab = A + (size_t)z * sA;
    const unsigned short* Bb = B + (size_t)z * sB;
    const int nk = K >> 6;

    __shared__ unsigned short As[2][256 * 64];
    __shared__ unsigned short Bs[2][256 * 64];

    const int tid = threadIdx.x;
    const int l = tid & 63, w = tid >> 6;
    const int wr = w >> 2, wc = w & 3;           // 2M x 4N
    const int m0 = mt * 256, n0 = nt * 256;

    // staging address math (pre-swizzled source; linear LDS dest)
    const int srow = w * 8 + (l >> 3);                 // row within 64-row round
    const int scol = ((l & 7) ^ (l >> 3)) * 8;         // pre-swizzled col (elems)
    const size_t ldst = (size_t)w * 1024 + (size_t)l * 16;

    auto stageA = [&](int t, int h, int b) {           // half h of A K-tile t
        const unsigned short* src = Ab + (size_t)(m0 + h * 128 + srow) * lda + t * 64 + scol;
        char* dst = (char*)&As[b][0] + h * 16384 + ldst;
        gload_lds16(src, dst);
        gload_lds16(src + (size_t)64 * lda, dst + 8192);
    };
    auto stageB = [&](int t, int h, int b) {
        const unsigned short* src = Bb + (size_t)(n0 + h * 128 + srow) * ldb + t * 64 + scol;
        char* dst = (char*)&Bs[b][0] + h * 16384 + ldst;
        gload_lds16(src, dst);
        gload_lds16(src + (size_t)64 * ldb, dst + 8192);
    };

    // frag read offsets (swizzled): slot = (kk*4 + l>>4) ^ (l&7)
    const int l15 = l & 15, l7 = l & 7;
    const int s0 = (((l >> 4) ^ l7) * 16);
    const int s1 = ((((l >> 4) + 4) ^ l7) * 16);

    f32x4 acc[8][4] = {};
    bf16x8 Af[4][2], Bf0[2][2], Bf1[2][2];

    // prologue: tile0 fully (buf0), B-halves of tile1 (buf1); vmcnt(4)
    stageA(0, 0, 0); stageA(0, 1, 0); stageB(0, 0, 0); stageB(0, 1, 0);
    if (nk > 1) {
        stageB(1, 0, 1); stageB(1, 1, 1);
        asm volatile("s_waitcnt vmcnt(4)" ::: "memory");
    } else {
        asm volatile("s_waitcnt vmcnt(0)" ::: "memory");
    }
    SB(); BAR(); SB();

    for (int t = 0; t < nk; ++t) {
        const int b = t & 1, bn = b ^ 1;
        const char* ab = (const char*)&As[b][0] + (wr * 128 + l15) * 128;
        const char* bb = (const char*)&Bs[b][0] + (wc * 64 + l15) * 128;

        // ---- P1: Q(0,0). reads: A qm0 (8) + B qn0 (4); stage A0(t+1)
        #pragma unroll
        for (int mi = 0; mi < 4; ++mi) {
            Af[mi][0] = *(const bf16x8*)(ab + mi * 2048 + s0);
            Af[mi][1] = *(const bf16x8*)(ab + mi * 2048 + s1);
        }
        #pragma unroll
        for (int ni = 0; ni < 2; ++ni) {
            Bf0[ni][0] = *(const bf16x8*)(bb + ni * 2048 + s0);
            Bf0[ni][1] = *(const bf16x8*)(bb + ni * 2048 + s1);
        }
        if (t + 1 < nk) stageA(t + 1, 0, bn);
        BAR(); LGKM0(); SB();
        __builtin_amdgcn_s_setprio(1);
        #pragma unroll
        for (int mi = 0; mi < 4; ++mi)
            #pragma unroll
            for (int ni = 0; ni < 2; ++ni) {
                acc[mi][ni] = MFMA(Af[mi][0], Bf0[ni][0], acc[mi][ni]);
                acc[mi][ni] = MFMA(Af[mi][1], Bf0[ni][1], acc[mi][ni]);
            }
        __builtin_amdgcn_s_setprio(0);
        SB(); BAR(); SB();

        // ---- P2: Q(0,1). reads: B qn1 (4); stage A1(t+1)
        #pragma unroll
        for (int ni = 0; ni < 2; ++ni) {
            Bf1[ni][0] = *(const bf16x8*)(bb + 4096 + ni * 2048 + s0);
            Bf1[ni][1] = *(const bf16x8*)(bb + 4096 + ni * 2048 + s1);
        }
        if (t + 1 < nk) stageA(t + 1, 1, bn);
        BAR(); LGKM0(); SB();
        __builtin_amdgcn_s_setprio(1);
        #pragma unroll
        for (int mi = 0; mi < 4; ++mi)
            #pragma unroll
            for (int ni = 0; ni < 2; ++ni) {
                acc[mi][2 + ni] = MFMA(Af[mi][0], Bf1[ni][0], acc[mi][2 + ni]);
                acc[mi][2 + ni] = MFMA(Af[mi][1], Bf1[ni][1], acc[mi][2 + ni]);
            }
        __builtin_amdgcn_s_setprio(0);
        SB(); BAR(); SB();

        // ---- P3: Q(1,1). reads: A qm1 (8, overwrite Af); stage B0(t+2) into b
        #pragma unroll
        for (int mi = 0; mi < 4; ++mi) {
            Af[mi][0] = *(const bf16x8*)(ab + 8192 + mi * 2048 + s0);
            Af[mi][1] = *(const bf16x8*)(ab + 8192 + mi * 2048 + s1);
        }
        if (t + 2 < nk) stageB(t + 2, 0, b);
        BAR(); LGKM0(); SB();
        __builtin_amdgcn_s_setprio(1);
        #pragma unroll
        for (int mi = 0; mi < 4; ++mi)
            #pragma unroll
            for (int ni = 0; ni < 2; ++ni) {
                acc[4 + mi][2 + ni] = MFMA(Af[mi][0], Bf1[ni][0], acc[4 + mi][2 + ni]);
                acc[4 + mi][2 + ni] = MFMA(Af[mi][1], Bf1[ni][1], acc[4 + mi][2 + ni]);
            }
        __builtin_amdgcn_s_setprio(0);
        SB(); BAR(); SB();

        // ---- P4: Q(1,0). no reads (Af from P3, Bf0 from P1); stage B1(t+2)
        if (t + 2 < nk) stageB(t + 2, 1, b);
        BAR(); SB();
        __builtin_amdgcn_s_setprio(1);
        #pragma unroll
        for (int mi = 0; mi < 4; ++mi)
            #pragma unroll
            for (int ni = 0; ni < 2; ++ni) {
                acc[4 + mi][ni] = MFMA(Af[mi][0], Bf0[ni][0], acc[4 + mi][ni]);
                acc[4 + mi][ni] = MFMA(Af[mi][1], Bf0[ni][1], acc[4 + mi][ni]);
            }
        __builtin_amdgcn_s_setprio(0);
        if (t + 2 < nk) {
            asm volatile("s_waitcnt vmcnt(4)" ::: "memory");   // tile t+1 landed
        } else if (t + 1 < nk) {
            asm volatile("s_waitcnt vmcnt(0)" ::: "memory");   // final drain
        }
        SB(); BAR(); SB();
    }

    // epilogue: C/D layout col = lane&15, row = (lane>>4)*4 + reg
    const int crow = (l >> 4) * 4, ccol = l & 15;
    if (MODE == 1) {
        unsigned short* C = (unsigned short*)C0 + (size_t)z * sC;
        #pragma unroll
        for (int mi = 0; mi < 8; ++mi)
            #pragma unroll
            for (int ni = 0; ni < 4; ++ni) {
                const size_t rbase = (size_t)(m0 + wr * 128 + mi * 16 + crow);
                const size_t cg = (size_t)(n0 + wc * 64 + ni * 16 + ccol);
                #pragma unroll
                for (int r = 0; r < 4; ++r)
                    C[(rbase + r) * ldc + cg] = f2bf(acc[mi][ni][r]);
            }
    } else { // MODE 3: fused QKV, BN=256: nt<4 Q, nt<8 K, else V transposed
        if (nt < 8) {
            unsigned short* C = (unsigned short*)(nt < 4 ? C0 : C1);
            const int cb = (nt < 4) ? n0 : n0 - 1024;
            #pragma unroll
            for (int mi = 0; mi < 8; ++mi)
                #pragma unroll
                for (int ni = 0; ni < 4; ++ni) {
                    const size_t rbase = (size_t)(m0 + wr * 128 + mi * 16 + crow);
                    const size_t cg = (size_t)(cb + wc * 64 + ni * 16 + ccol);
                    #pragma unroll
                    for (int r = 0; r < 4; ++r)
                        C[(rbase + r) * ldc + cg] = f2bf(acc[mi][ni][r]);
                }
        } else {
            unsigned short* Vt = (unsigned short*)C2;   // [1024][8192]
            #pragma unroll
            for (int mi = 0; mi < 8; ++mi)
                #pragma unroll
                for (int ni = 0; ni < 4; ++ni) {
                    const int rbase = m0 + wr * 128 + mi * 16 + crow;
                    const int o = (n0 - 2048) + wc * 64 + ni * 16 + ccol;
                    ushort4 u;
                    u.x = f2bf(acc[mi][ni][0]);
                    u.y = f2bf(acc[mi][ni][1]);
                    u.z = f2bf(acc[mi][ni][2]);
                    u.w = f2bf(acc[mi][ni][3]);
                    *reinterpret_cast<ushort4*>(&Vt[(size_t)o * 8192 + rbase]) = u;
                }
        }
    }
}

// ======== PV GEMM (R2-proven): 128x128, BK=32, 2-phase dbuf ========
// out[q][o] = sum_k P[q][k] * Vt[o][k]; fp32 out, causal Keff = (mt+1)*128
__global__ __launch_bounds__(256) void gemm128_pv(
    const unsigned short* __restrict__ A, int lda, long long sA,
    const unsigned short* __restrict__ B, int ldb, long long sB,
    float* __restrict__ C, int ldc, long long sC, int K)
{
    int mt, nt, z;
    xcd_swizzle(mt, nt, z);
    const unsigned short* Ab = A + (size_t)z * sA;
    const unsigned short* Bb = B + (size_t)z * sB;
    const int Keff = ((mt + 1) * 128 < K) ? (mt + 1) * 128 : K;
    const int nk = Keff >> 5;

    __shared__ unsigned short As[2][128 * 32];
    __shared__ unsigned short Bs[2][128 * 32];

    const int tid = threadIdx.x;
    const int l = tid & 63, w = tid >> 6;
    const int wr = w >> 1, wc = w & 1;
    const int m0 = mt * 128, n0 = nt * 128;
    const int lrow = l & 15, lsub = l >> 4;

    f32x4 acc[4][4] = {};

    auto stage = [&](int t, int b) {
        const int k0 = t * 32;
        #pragma unroll
        for (int j = 0; j < 2; ++j) {
            const int cc = (j * 4 + w) * 64 + l;
            const int row = cc >> 2, sub = cc & 3;
            gload_lds16(Ab + (size_t)(m0 + row) * lda + k0 + sub * 8,
                        (char*)&As[b][0] + (size_t)(j * 4 + w) * 1024);
            gload_lds16(Bb + (size_t)(n0 + row) * ldb + k0 + sub * 8,
                        (char*)&Bs[b][0] + (size_t)(j * 4 + w) * 1024);
        }
    };

    stage(0, 0);
    __syncthreads();
    int buf = 0;
    for (int t = 0; t < nk; ++t) {
        if (t + 1 < nk) stage(t + 1, buf ^ 1);

        bf16x8 af[4], bfr[4];
        #pragma unroll
        for (int m = 0; m < 4; ++m)
            af[m] = *reinterpret_cast<const bf16x8*>(&As[buf][(wr * 64 + m * 16 + lrow) * 32 + lsub * 8]);
        #pragma unroll
        for (int n = 0; n < 4; ++n)
            bfr[n] = *reinterpret_cast<const bf16x8*>(&Bs[buf][(wc * 64 + n * 16 + lrow) * 32 + lsub * 8]);

        #pragma unroll
        for (int m = 0; m < 4; ++m)
            #pragma unroll
            for (int n = 0; n < 4; ++n)
                acc[m][n] = MFMA(af[m], bfr[n], acc[m][n]);

        __syncthreads();
        buf ^= 1;
    }

    const int crow = (l >> 4) * 4, ccol = l & 15;
    float* Cb = C + (size_t)z * sC;
    #pragma unroll
    for (int m = 0; m < 4; ++m)
        #pragma unroll
        for (int n = 0; n < 4; ++n) {
            const size_t rbase = (size_t)(m0 + wr * 64 + m * 16 + crow);
            const size_t cg = (size_t)(n0 + wc * 64 + n * 16 + ccol);
            #pragma unroll
            for (int r = 0; r < 4; ++r)
                Cb[(rbase + r) * ldc + cg] = acc[m][n][r];
        }
}

// ---------------- causal row softmax, in-place on bf16 scores ----------------
// reads cols <= q, writes cols < ((q>>7)+1)*128 (the PV kernel's read extent)
__global__ __launch_bounds__(256) void softmax_causal(unsigned short* __restrict__ P) {
    const int S = 2048;
    const int gq = blockIdx.x;
    const int q = gq & (S - 1);
    unsigned short* row = P + (size_t)gq * S;
    const int t = threadIdx.x;
    const int c0 = t * 8;
    const int l = t & 63, w = t >> 6;
    const int wlim = ((q >> 7) + 1) << 7;
    const float NEG = -__builtin_huge_valf();

    float f[8];
    if (c0 <= q) {
        uint4 rv = *reinterpret_cast<const uint4*>(row + c0);
        unsigned short us[8];
        us[0] = rv.x & 0xffff; us[1] = rv.x >> 16;
        us[2] = rv.y & 0xffff; us[3] = rv.y >> 16;
        us[4] = rv.z & 0xffff; us[5] = rv.z >> 16;
        us[6] = rv.w & 0xffff; us[7] = rv.w >> 16;
        #pragma unroll
        for (int i = 0; i < 8; ++i)
            f[i] = (c0 + i <= q) ? bf2f(us[i]) : NEG;
    } else {
        #pragma unroll
        for (int i = 0; i < 8; ++i) f[i] = NEG;
    }

    float m = f[0];
    #pragma unroll
    for (int i = 1; i < 8; ++i) m = fmaxf(m, f[i]);
    #pragma unroll
    for (int o = 1; o < 64; o <<= 1) m = fmaxf(m, __shfl_xor(m, o));

    __shared__ float smax[4], ssum[4];
    if (l == 0) smax[w] = m;
    __syncthreads();
    m = fmaxf(fmaxf(smax[0], smax[1]), fmaxf(smax[2], smax[3]));

    float e[8];
    float s = 0.f;
    #pragma unroll
    for (int i = 0; i < 8; ++i) {
        e[i] = exp2f((f[i] - m) * 1.44269504f);
        s += e[i];
    }
    #pragma unroll
    for (int o = 1; o < 64; o <<= 1) s += __shfl_xor(s, o);
    if (l == 0) ssum[w] = s;
    __syncthreads();
    s = ssum[0] + ssum[1] + ssum[2] + ssum[3];
    const float inv = 1.0f / s;

    if (c0 < wlim) {
        uint4 ov;
        ov.x = f2bf(e[0] * inv) | ((unsigned int)f2bf(e[1] * inv) << 16);
        ov.y = f2bf(e[2] * inv) | ((unsigned int)f2bf(e[3] * inv) << 16);
        ov.z = f2bf(e[4] * inv) | ((unsigned int)f2bf(e[5] * inv) << 16);
        ov.w = f2bf(e[6] * inv) | ((unsigned int)f2bf(e[7] * inv) << 16);
        *reinterpret_cast<uint4*>(row + c0) = ov;
    }
}

extern "C" void kernel_launch(void* const* d_in, const int* in_sizes, int n_in,
                              void* d_out, int out_size, void* d_ws, size_t ws_size,
                              hipStream_t stream) {
    const float* x  = (const float*)d_in[0];
    const float* Wq = (const float*)d_in[1];
    const float* Wk = (const float*)d_in[2];
    const float* Wv = (const float*)d_in[3];
    float* out = (float*)d_out;

    const int Bz = 4, S = 2048, D = 1024;
    const int MS = Bz * S;       // 8192
    const int DD = D * D;

    char* ws = (char*)d_ws;
    unsigned short* xb   = (unsigned short*)(ws);                      // 16 MB [8192][1024]
    unsigned short* wqkv = (unsigned short*)(ws + (16ull << 20));      //  6 MB [3072][1024]
    unsigned short* qb   = (unsigned short*)(ws + (22ull << 20));      // 16 MB [8192][1024]
    unsigned short* kb   = (unsigned short*)(ws + (38ull << 20));      // 16 MB [8192][1024]
    unsigned short* vt   = (unsigned short*)(ws + (54ull << 20));      // 16 MB [1024][8192] (V^T)
    unsigned short* sc   = (unsigned short*)(ws + (70ull << 20));      // 32 MB [4][2048][2048]

    // 1. bf16 conversion; fold softmax scale 1/sqrt(D)=1/32 into Wq
    cvt_kernel<<<2048, 256, 0, stream>>>(x,  xb, MS * D / 4, 1.0f);
    cvt_kernel<<<512,  256, 0, stream>>>(Wq, wqkv,          DD / 4, 0.03125f);
    cvt_kernel<<<512,  256, 0, stream>>>(Wk, wqkv + DD,     DD / 4, 1.0f);
    cvt_kernel<<<512,  256, 0, stream>>>(Wv, wqkv + 2 * DD, DD / 4, 1.0f);

    // 2. fused QKV projection: [8192][3072] = xb * Wqkv^T; V stored transposed
    gemm256<3><<<dim3(MS / 256, 12, 1), 512, 0, stream>>>(
        xb, D, 0, wqkv, D, 0, qb, kb, vt, D, 0, D);

    // 3. scores = Q * K^T per batch (bf16 out), skip strictly-upper 256-tiles
    gemm256<1><<<dim3(S / 256, S / 256, Bz), 512, 0, stream>>>(
        qb, D, (long long)S * D, kb, D, (long long)S * D, sc, nullptr, nullptr,
        S, (long long)S * S, D);

    // 4. causal softmax in place (zero-fills up to the PV read extent)
    softmax_causal<<<MS, 256, 0, stream>>>(sc);

    // 5. out = P * V == P * Vt^T  (128x128 2-phase kernel, causal K-limit)
    gemm128_pv<<<dim3(S / 128, D / 128, Bz), 256, 0, stream>>>(
        sc, S, (long long)S * S, vt, MS, S, out, D, (long long)S * D, S);
}